// Round 2
// baseline (1328.964 us; speedup 1.0000x reference)
//
#include <hip/hip_runtime.h>
#include <stdint.h>

// ---------------- types & helpers ----------------
typedef __bf16 v8bf __attribute__((ext_vector_type(8)));
typedef float  v4f  __attribute__((ext_vector_type(4)));

__device__ __forceinline__ float bf2f(uint16_t h) {
    union { uint32_t u; float f; } x; x.u = ((uint32_t)h) << 16; return x.f;
}
__device__ __forceinline__ uint16_t f2bf(float f) {
    union { float f; uint32_t u; } x; x.f = f;
    uint32_t r = x.u + 0x7fffu + ((x.u >> 16) & 1u);
    return (uint16_t)(r >> 16);
}

__device__ __forceinline__ void gload16(const uint16_t* g, uint16_t* l) {
    __builtin_amdgcn_global_load_lds((const __attribute__((address_space(1))) void*)g,
                                     (__attribute__((address_space(3))) void*)l, 16, 0, 0);
}

// ---------------- embed: h = tok_emb[x] + pos_emb ----------------
__global__ void k_embed(const int* __restrict__ x, const float* __restrict__ tok,
                        const float* __restrict__ pos, float* __restrict__ hf,
                        uint16_t* __restrict__ hb)
{
    int i = blockIdx.x;           // 0..2047  (b*1024 + t)
    int t = i & 1023;
    int tk = x[i];
    const float* te = tok + (long)tk * 768;
    const float* pe = pos + (long)t * 768;
    for (int j = threadIdx.x; j < 768; j += 256) {
        float v = te[j] + pe[j];
        hf[(long)i * 768 + j] = v;
        hb[(long)i * 768 + j] = f2bf(v);
    }
}

// ---------------- transpose + cast to bf16: dst[c][r] = src[r][c] ----------------
// grid (C/32, R/32, nbatch), block (32,8)
template<typename SrcT>
__global__ void k_transpose(const SrcT* __restrict__ src, uint16_t* __restrict__ dst,
                            int ldS, int ldD, long sBatch, long dBatch)
{
    __shared__ float tile[32][33];
    src += (long)blockIdx.z * sBatch;
    dst += (long)blockIdx.z * dBatch;
    int c0 = blockIdx.x * 32, r0 = blockIdx.y * 32;
    int tx = threadIdx.x, ty = threadIdx.y;
    #pragma unroll
    for (int i = 0; i < 4; ++i) {
        int r = r0 + ty + i * 8;
        SrcT s = src[(long)r * ldS + c0 + tx];
        float v;
        if constexpr (sizeof(SrcT) == 4) v = (float)s; else v = bf2f((uint16_t)s);
        tile[ty + i * 8][tx] = v;
    }
    __syncthreads();
    #pragma unroll
    for (int i = 0; i < 4; ++i) {
        int c = c0 + ty + i * 8;
        dst[(long)c * ldD + r0 + tx] = f2bf(tile[tx][ty + i * 8]);
    }
}

// ---------------- concat qkv biases for all layers: grid (3, L) ----------------
__global__ void k_concat3(const float* __restrict__ a, const float* __restrict__ b,
                          const float* __restrict__ c, float* __restrict__ out)
{
    int l = blockIdx.y;
    const float* s = (blockIdx.x == 0) ? a : ((blockIdx.x == 1) ? b : c);
    s += (long)l * 768;
    for (int j = threadIdx.x; j < 768; j += 256)
        out[(long)l * 2304 + blockIdx.x * 768 + j] = s[j];
}

// ---------------- GEMM: C = A[M,K] @ BT[N,K]^T * scale (+bias) (+res) (relu) ----------
// A, BT bf16 (k-contiguous rows). 128x128 tile, BK=32, 256 threads (4 waves, 2x2).
// grid (Ntiles, Mtiles, batch). causal: 0 none, 1 skip nt>mt, 2 clamp K to (mt+1)*128.
template<typename OutT, bool BIAS, bool RELU, bool RES>
__global__ void k_gemm(const uint16_t* __restrict__ A, const uint16_t* __restrict__ BT,
                       OutT* __restrict__ C, const float* __restrict__ bias,
                       const float* __restrict__ res,
                       int K, int lda, int ldb, int ldc,
                       long bsA, long bsB, long bsC, float scale, int causal)
{
    // XCD-chunked bijective swizzle + m-tile-fastest decomposition (B-tile reuse in L2)
    const int nwg = gridDim.x * gridDim.y;
    int lin = blockIdx.y * gridDim.x + blockIdx.x;
    {
        int q = nwg >> 3, r = nwg & 7, x = lin & 7, i = lin >> 3;
        lin = (x < r ? x * (q + 1) : r * (q + 1) + (x - r) * q) + i;
    }
    const int mt = lin % gridDim.y;   // gridDim.y is pow2 in all our launches
    const int nt = lin / gridDim.y;

    if (causal == 1 && nt > mt) return;
    const int Keff = (causal == 2) ? ((mt + 1) * 128 < K ? (mt + 1) * 128 : K) : K;

    __shared__ uint16_t As[128 * 32];
    __shared__ uint16_t Bs[128 * 32];
    const int tid  = threadIdx.x;
    const int lane = tid & 63;
    const int bz   = blockIdx.z;
    const uint16_t* Ab = A + (long)bz * bsA + (long)mt * 128 * lda;
    const uint16_t* Bb = BT + (long)bz * bsB + (long)nt * 128 * ldb;

    const int wm = (tid >> 6) >> 1, wn = (tid >> 6) & 1;   // wave 2x2 -> 64x64 each
    const int fr = lane & 15, fq = lane >> 4;

    const int r0 = tid >> 2;           // staging row 0..63
    const int s0 = (tid & 3) * 8;      // staging k-slot (elements)

    v4f acc[4][4];
    #pragma unroll
    for (int m = 0; m < 4; ++m)
        #pragma unroll
        for (int n = 0; n < 4; ++n) acc[m][n] = (v4f){0.f, 0.f, 0.f, 0.f};

    for (int kt = 0; kt < Keff; kt += 32) {
        gload16(Ab + (long)r0 * lda + kt + s0,        &As[tid * 8]);
        gload16(Ab + (long)(r0 + 64) * lda + kt + s0, &As[2048 + tid * 8]);
        gload16(Bb + (long)r0 * ldb + kt + s0,        &Bs[tid * 8]);
        gload16(Bb + (long)(r0 + 64) * ldb + kt + s0, &Bs[2048 + tid * 8]);
        __syncthreads();
        v8bf ag[4], bg[4];
        #pragma unroll
        for (int m = 0; m < 4; ++m)
            ag[m] = *(const v8bf*)&As[(wm * 64 + m * 16 + fr) * 32 + fq * 8];
        #pragma unroll
        for (int n = 0; n < 4; ++n)
            bg[n] = *(const v8bf*)&Bs[(wn * 64 + n * 16 + fr) * 32 + fq * 8];
        #pragma unroll
        for (int m = 0; m < 4; ++m)
            #pragma unroll
            for (int n = 0; n < 4; ++n)
                acc[m][n] = __builtin_amdgcn_mfma_f32_16x16x32_bf16(ag[m], bg[n], acc[m][n], 0, 0, 0);
        __syncthreads();
    }

    OutT* Cb = C + (long)bz * bsC + (long)mt * 128 * ldc + nt * 128;
    const float* Rb = RES ? (res + (long)bz * bsC + (long)mt * 128 * ldc + nt * 128) : nullptr;
    #pragma unroll
    for (int n = 0; n < 4; ++n) {
        int col = wn * 64 + n * 16 + fr;
        float bv = BIAS ? bias[nt * 128 + col] : 0.f;
        #pragma unroll
        for (int m = 0; m < 4; ++m) {
            #pragma unroll
            for (int r = 0; r < 4; ++r) {
                int row = wm * 64 + m * 16 + fq * 4 + r;
                float v = acc[m][n][r] * scale + bv;
                if (RES) v += Rb[(long)row * ldc + col];
                if (RELU) v = fmaxf(v, 0.f);
                if constexpr (sizeof(OutT) == 4) Cb[(long)row * ldc + col] = v;
                else                             Cb[(long)row * ldc + col] = f2bf(v);
            }
        }
    }
}

// ---------------- causal softmax over rows of [B,T,T], writes bf16 probs ----------------
// grid (T, B), block 256; row t allows s<=t. (+1.0 constant in ref is softmax-invariant.)
// Writes only up to the 128-tile boundary (PV clamps K there).
__global__ void k_softmax(const float* __restrict__ S, uint16_t* __restrict__ P)
{
    int t = blockIdx.x, b = blockIdx.y;
    const float* row = S + ((long)b * 1024 + t) * 1024;
    uint16_t* pr = P + ((long)b * 1024 + t) * 1024;
    int limit = (t & ~127) + 128;
    int s0 = threadIdx.x * 4;
    float vals[4] = {0.f, 0.f, 0.f, 0.f};
    if (s0 < limit) {
        float4 vv = *(const float4*)(row + s0);
        vals[0] = vv.x; vals[1] = vv.y; vals[2] = vv.z; vals[3] = vv.w;
    }
    float mx = -1e30f;
    #pragma unroll
    for (int j = 0; j < 4; ++j) if (s0 + j <= t) mx = fmaxf(mx, vals[j]);
    #pragma unroll
    for (int o = 32; o; o >>= 1) mx = fmaxf(mx, __shfl_xor(mx, o));
    __shared__ float red[8];
    int wave = threadIdx.x >> 6, lane = threadIdx.x & 63;
    if (lane == 0) red[wave] = mx;
    __syncthreads();
    mx = fmaxf(fmaxf(red[0], red[1]), fmaxf(red[2], red[3]));
    float e[4]; float sum = 0.f;
    #pragma unroll
    for (int j = 0; j < 4; ++j) { e[j] = (s0 + j <= t) ? __expf(vals[j] - mx) : 0.f; sum += e[j]; }
    #pragma unroll
    for (int o = 32; o; o >>= 1) sum += __shfl_xor(sum, o);
    if (lane == 0) red[4 + wave] = sum;
    __syncthreads();
    sum = red[4] + red[5] + red[6] + red[7];
    float inv = 1.f / sum;
    if (s0 < limit) {
        #pragma unroll
        for (int j = 0; j < 4; ++j) pr[s0 + j] = f2bf(e[j] * inv);
    }
}

// ---------------- layernorm of a single f32 tensor: out = LN(a)*w + bias ----------------
__global__ void k_ln(const float* __restrict__ a,
                     const float* __restrict__ w, const float* __restrict__ bias,
                     float* __restrict__ outf, uint16_t* __restrict__ outb)
{
    int row = blockIdx.x;
    const float* ar = a + (long)row * 768;
    float v[3]; float s1 = 0.f, s2 = 0.f;
    #pragma unroll
    for (int i = 0; i < 3; ++i) {
        int e = threadIdx.x + i * 256;
        v[i] = ar[e];
        s1 += v[i]; s2 += v[i] * v[i];
    }
    #pragma unroll
    for (int o = 32; o; o >>= 1) { s1 += __shfl_xor(s1, o); s2 += __shfl_xor(s2, o); }
    __shared__ float red[8];
    int wave = threadIdx.x >> 6, lane = threadIdx.x & 63;
    if (lane == 0) { red[wave] = s1; red[4 + wave] = s2; }
    __syncthreads();
    s1 = red[0] + red[1] + red[2] + red[3];
    s2 = red[4] + red[5] + red[6] + red[7];
    float mean = s1 * (1.f / 768.f);
    float var  = s2 * (1.f / 768.f) - mean * mean;
    float rstd = rsqrtf(var + 1e-5f);
    #pragma unroll
    for (int i = 0; i < 3; ++i) {
        int e = threadIdx.x + i * 256;
        float o = (v[i] - mean) * rstd * w[e] + bias[e];
        outf[(long)row * 768 + e] = o;
        outb[(long)row * 768 + e] = f2bf(o);
    }
}

// ---------------- host ----------------
extern "C" void kernel_launch(void* const* d_in, const int* in_sizes, int n_in,
                              void* d_out, int out_size, void* d_ws, size_t ws_size,
                              hipStream_t stream)
{
    const int*   x       = (const int*)d_in[0];
    const float* tok_emb = (const float*)d_in[1];
    const float* pos_emb = (const float*)d_in[2];
    const float* Wq  = (const float*)d_in[3];
    const float* bq  = (const float*)d_in[4];
    const float* Wk  = (const float*)d_in[5];
    const float* bk  = (const float*)d_in[6];
    const float* Wv  = (const float*)d_in[7];
    const float* bv  = (const float*)d_in[8];
    const float* ln1w = (const float*)d_in[9];
    const float* ln1b = (const float*)d_in[10];
    const float* W1  = (const float*)d_in[11];
    const float* b1  = (const float*)d_in[12];
    const float* W2  = (const float*)d_in[13];
    const float* b2  = (const float*)d_in[14];
    const float* ln2w = (const float*)d_in[15];
    const float* ln2b = (const float*)d_in[16];
    const float* Wo  = (const float*)d_in[17];
    const float* bo  = (const float*)d_in[18];
    float* out = (float*)d_out;
    (void)in_sizes; (void)n_in; (void)out_size;

    char* ws = (char*)d_ws;
    size_t off = 0;
    auto alloc = [&](size_t bytes) -> char* {
        char* p = ws + off;
        off = (off + bytes + 255) & ~(size_t)255;
        return p;
    };
    uint16_t* WoT   = (uint16_t*)alloc(32000L * 768 * 2);
    float*    hf    = (float*)alloc(2048L * 768 * 4);
    uint16_t* hb    = (uint16_t*)alloc(2048L * 768 * 2);
    uint16_t* qkv   = (uint16_t*)alloc(2048L * 2304 * 2);
    uint16_t* vT    = (uint16_t*)alloc(2L * 768 * 1024 * 2);
    float*    sc    = (float*)alloc(2L * 1024 * 1024 * 4);
    uint16_t* pr    = (uint16_t*)alloc(2L * 1024 * 1024 * 2);
    float*    hsum  = (float*)alloc(2048L * 768 * 4);   // h + att (post-PV, residual fused)
    float*    h1f   = (float*)alloc(2048L * 768 * 4);
    uint16_t* h1b   = (uint16_t*)alloc(2048L * 768 * 2);
    uint16_t* f1    = (uint16_t*)alloc(2048L * 3072 * 2);
    float*    f2s   = (float*)alloc(2048L * 768 * 4);   // ffn + h1 (residual fused)
    float*    bqkvA = (float*)alloc(6L * 2304 * 4);

    // try to hoist all weight transposes (z=6 batched) — needs ~197 MB total ws
    size_t mark = off;
    uint16_t* WqkvTA = (uint16_t*)alloc(6L * 2304 * 768 * 2);
    uint16_t* W1TA   = (uint16_t*)alloc(6L * 3072 * 768 * 2);
    uint16_t* W2TA   = (uint16_t*)alloc(6L * 768 * 3072 * 2);
    bool hoist = (off <= ws_size);
    uint16_t *WqkvT = nullptr, *W1T = nullptr, *W2T = nullptr;
    if (!hoist) {
        off = mark;
        WqkvT = (uint16_t*)alloc(2304L * 768 * 2);
        W1T   = (uint16_t*)alloc(3072L * 768 * 2);
        W2T   = (uint16_t*)alloc(768L * 3072 * 2);
    }

    dim3 tb(32, 8);
    const float iscale = 0.036084391824351615f;  // 1/sqrt(768)
    const long EE = 768L * 768;

    // Wo^T (once): src [768][32000] -> dst [32000][768]
    k_transpose<float><<<dim3(1000, 24, 1), tb, 0, stream>>>(Wo, WoT, 32000, 768, 0, 0);
    k_embed<<<2048, 256, 0, stream>>>(x, tok_emb, pos_emb, hf, hb);
    k_concat3<<<dim3(3, 6), 256, 0, stream>>>(bq, bk, bv, bqkvA);

    if (hoist) {
        k_transpose<float><<<dim3(24, 24, 6), tb, 0, stream>>>(Wq, WqkvTA,             768, 768, EE, 2304L*768);
        k_transpose<float><<<dim3(24, 24, 6), tb, 0, stream>>>(Wk, WqkvTA + 768L*768,  768, 768, EE, 2304L*768);
        k_transpose<float><<<dim3(24, 24, 6), tb, 0, stream>>>(Wv, WqkvTA + 1536L*768, 768, 768, EE, 2304L*768);
        k_transpose<float><<<dim3(96, 24, 6), tb, 0, stream>>>(W1, W1TA, 3072, 768, 768L*3072, 3072L*768);
        k_transpose<float><<<dim3(24, 96, 6), tb, 0, stream>>>(W2, W2TA, 768, 3072, 3072L*768, 768L*3072);
    }

    for (int l = 0; l < 6; ++l) {
        uint16_t* WqkvL = hoist ? (WqkvTA + l * 2304L * 768) : WqkvT;
        uint16_t* W1L   = hoist ? (W1TA   + l * 3072L * 768) : W1T;
        uint16_t* W2L   = hoist ? (W2TA   + l * 768L * 3072) : W2T;
        if (!hoist) {
            k_transpose<float><<<dim3(24, 24, 1), tb, 0, stream>>>(Wq + l * EE, WqkvT,             768, 768, 0, 0);
            k_transpose<float><<<dim3(24, 24, 1), tb, 0, stream>>>(Wk + l * EE, WqkvT + 768L*768,  768, 768, 0, 0);
            k_transpose<float><<<dim3(24, 24, 1), tb, 0, stream>>>(Wv + l * EE, WqkvT + 1536L*768, 768, 768, 0, 0);
            k_transpose<float><<<dim3(96, 24, 1), tb, 0, stream>>>(W1 + l * 768L * 3072, W1T, 3072, 768, 0, 0);
            k_transpose<float><<<dim3(24, 96, 1), tb, 0, stream>>>(W2 + l * 3072L * 768, W2T, 768, 3072, 0, 0);
        }

        // qkv = h @ [Wq|Wk|Wv] + bias   [2048, 2304] bf16
        k_gemm<uint16_t, true, false, false><<<dim3(18, 16, 1), 256, 0, stream>>>(
            hb, WqkvL, qkv, bqkvA + l * 2304, nullptr, 768, 768, 768, 2304, 0, 0, 0, 1.f, 0);
        // scores = Q @ K^T / sqrt(E), causal tile-skip, f32
        k_gemm<float, false, false, false><<<dim3(8, 8, 2), 256, 0, stream>>>(
            qkv, qkv + 768, sc, nullptr, nullptr, 768, 2304, 2304, 1024,
            1024L * 2304, 1024L * 2304, 1024L * 1024, iscale, 1);
        k_softmax<<<dim3(1024, 2), 256, 0, stream>>>(sc, pr);
        // V^T per batch: src [1024][768] (ld 2304) -> [768][1024]
        k_transpose<uint16_t><<<dim3(24, 32, 2), tb, 0, stream>>>(
            qkv + 1536, vT, 2304, 1024, 1024L * 2304, 768L * 1024);
        // hsum = P @ V + h   (K clamped causally), f32
        k_gemm<float, false, false, true><<<dim3(6, 8, 2), 256, 0, stream>>>(
            pr, vT, hsum, nullptr, hf, 1024, 1024, 1024, 768,
            1024L * 1024, 768L * 1024, 1024L * 768, 1.f, 2);
        k_ln<<<2048, 256, 0, stream>>>(hsum, ln1w + l * 768, ln1b + l * 768, h1f, h1b);
        // f1 = relu(h1 @ W1 + b1)  bf16
        k_gemm<uint16_t, true, true, false><<<dim3(24, 16, 1), 256, 0, stream>>>(
            h1b, W1L, f1, b1 + l * 3072, nullptr, 768, 768, 768, 3072, 0, 0, 0, 1.f, 0);
        // f2s = f1 @ W2 + b2 + h1  f32
        k_gemm<float, true, false, true><<<dim3(6, 16, 1), 256, 0, stream>>>(
            f1, W2L, f2s, b2 + l * 768, h1f, 3072, 3072, 3072, 768, 0, 0, 0, 1.f, 0);
        k_ln<<<2048, 256, 0, stream>>>(f2s, ln2w + l * 768, ln2b + l * 768, hf, hb);
    }

    // logits = h @ Wo + bo  -> f32 d_out [2048, 32000]
    k_gemm<float, true, false, false><<<dim3(250, 16, 1), 256, 0, stream>>>(
        hb, WoT, out, bo, nullptr, 768, 768, 768, 32000, 0, 0, 0, 1.f, 0);
}

// Round 3
// 969.923 us; speedup vs baseline: 1.3702x; 1.3702x over previous
//
#include <hip/hip_runtime.h>
#include <stdint.h>

// ---------------- types & helpers ----------------
typedef __bf16 v8bf __attribute__((ext_vector_type(8)));
typedef float  v4f  __attribute__((ext_vector_type(4)));

__device__ __forceinline__ float bf2f(uint16_t h) {
    union { uint32_t u; float f; } x; x.u = ((uint32_t)h) << 16; return x.f;
}
__device__ __forceinline__ uint16_t f2bf(float f) {
    union { float f; uint32_t u; } x; x.f = f;
    uint32_t r = x.u + 0x7fffu + ((x.u >> 16) & 1u);
    return (uint16_t)(r >> 16);
}

__device__ __forceinline__ void gload16(const uint16_t* g, uint16_t* l) {
    __builtin_amdgcn_global_load_lds((const __attribute__((address_space(1))) void*)g,
                                     (__attribute__((address_space(3))) void*)l, 16, 0, 0);
}

// ---------------- embed: h = tok_emb[x] + pos_emb ----------------
__global__ void k_embed(const int* __restrict__ x, const float* __restrict__ tok,
                        const float* __restrict__ pos, float* __restrict__ hf,
                        uint16_t* __restrict__ hb)
{
    int i = blockIdx.x;           // 0..2047  (b*1024 + t)
    int t = i & 1023;
    int tk = x[i];
    const float* te = tok + (long)tk * 768;
    const float* pe = pos + (long)t * 768;
    for (int j = threadIdx.x; j < 768; j += 256) {
        float v = te[j] + pe[j];
        hf[(long)i * 768 + j] = v;
        hb[(long)i * 768 + j] = f2bf(v);
    }
}

// ---------------- transpose + cast to bf16: dst[c][r] = src[r][c] ----------------
// grid (C/32, R/32, nbatch), block (32,8)
template<typename SrcT>
__global__ void k_transpose(const SrcT* __restrict__ src, uint16_t* __restrict__ dst,
                            int ldS, int ldD, long sBatch, long dBatch)
{
    __shared__ float tile[32][33];
    src += (long)blockIdx.z * sBatch;
    dst += (long)blockIdx.z * dBatch;
    int c0 = blockIdx.x * 32, r0 = blockIdx.y * 32;
    int tx = threadIdx.x, ty = threadIdx.y;
    #pragma unroll
    for (int i = 0; i < 4; ++i) {
        int r = r0 + ty + i * 8;
        SrcT s = src[(long)r * ldS + c0 + tx];
        float v;
        if constexpr (sizeof(SrcT) == 4) v = (float)s; else v = bf2f((uint16_t)s);
        tile[ty + i * 8][tx] = v;
    }
    __syncthreads();
    #pragma unroll
    for (int i = 0; i < 4; ++i) {
        int c = c0 + ty + i * 8;
        dst[(long)c * ldD + r0 + tx] = f2bf(tile[tx][ty + i * 8]);
    }
}

// ---------------- concat qkv biases for all layers: grid (3, L) ----------------
__global__ void k_concat3(const float* __restrict__ a, const float* __restrict__ b,
                          const float* __restrict__ c, float* __restrict__ out)
{
    int l = blockIdx.y;
    const float* s = (blockIdx.x == 0) ? a : ((blockIdx.x == 1) ? b : c);
    s += (long)l * 768;
    for (int j = threadIdx.x; j < 768; j += 256)
        out[(long)l * 2304 + blockIdx.x * 768 + j] = s[j];
}

// ---------------- GEMM: C = A[M,K] @ BT[N,K]^T * scale (+bias) (+res) (relu) ----------
// A, BT bf16 (k-contiguous rows). 128xBN tile, BK=32, 256 threads (4 waves, 2x2).
// grid (Ntiles, Mtiles, batch). causal: 0 none, 1 skip fully-masked tiles,
// 2 clamp K to (mt+1)*128. Split-K trick: pass bsA=bsB=k-chunk stride, K=chunk.
template<typename OutT, int BN, bool BIAS, bool RELU, bool RES>
__global__ void k_gemm(const uint16_t* __restrict__ A, const uint16_t* __restrict__ BT,
                       OutT* __restrict__ C, const float* __restrict__ bias,
                       const float* __restrict__ res,
                       int K, int lda, int ldb, int ldc,
                       long bsA, long bsB, long bsC, float scale, int causal)
{
    constexpr int NT = BN / 32;       // per-wave n-tiles (wave covers BN/2 cols)
    // XCD-chunked bijective swizzle + m-tile-fastest decomposition (B-tile reuse in L2)
    const int nwg = gridDim.x * gridDim.y;
    int lin = blockIdx.y * gridDim.x + blockIdx.x;
    {
        int q = nwg >> 3, r = nwg & 7, x = lin & 7, i = lin >> 3;
        lin = (x < r ? x * (q + 1) : r * (q + 1) + (x - r) * q) + i;
    }
    const int mt = lin % gridDim.y;   // gridDim.y is pow2 in all our launches
    const int nt = lin / gridDim.y;

    if (causal == 1 && nt * BN >= (mt + 1) * 128) return;
    const int Keff = (causal == 2) ? ((mt + 1) * 128 < K ? (mt + 1) * 128 : K) : K;

    __shared__ uint16_t As[128 * 32];
    __shared__ uint16_t Bs[BN * 32];
    const int tid  = threadIdx.x;
    const int lane = tid & 63;
    const int bz   = blockIdx.z;
    const uint16_t* Ab = A + (long)bz * bsA + (long)mt * 128 * lda;
    const uint16_t* Bb = BT + (long)bz * bsB + (long)nt * BN * ldb;

    const int wm = (tid >> 6) >> 1, wn = (tid >> 6) & 1;   // wave 2x2
    const int fr = lane & 15, fq = lane >> 4;

    const int r0 = tid >> 2;           // staging row 0..63
    const int s0 = (tid & 3) * 8;      // staging k-slot (elements)

    v4f acc[4][NT];
    #pragma unroll
    for (int m = 0; m < 4; ++m)
        #pragma unroll
        for (int n = 0; n < NT; ++n) acc[m][n] = (v4f){0.f, 0.f, 0.f, 0.f};

    for (int kt = 0; kt < Keff; kt += 32) {
        gload16(Ab + (long)r0 * lda + kt + s0,        &As[tid * 8]);
        gload16(Ab + (long)(r0 + 64) * lda + kt + s0, &As[2048 + tid * 8]);
        gload16(Bb + (long)r0 * ldb + kt + s0,        &Bs[tid * 8]);
        if constexpr (BN == 128)
            gload16(Bb + (long)(r0 + 64) * ldb + kt + s0, &Bs[2048 + tid * 8]);
        __syncthreads();
        v8bf ag[4], bg[NT];
        #pragma unroll
        for (int m = 0; m < 4; ++m)
            ag[m] = *(const v8bf*)&As[(wm * 64 + m * 16 + fr) * 32 + fq * 8];
        #pragma unroll
        for (int n = 0; n < NT; ++n)
            bg[n] = *(const v8bf*)&Bs[(wn * (BN / 2) + n * 16 + fr) * 32 + fq * 8];
        #pragma unroll
        for (int m = 0; m < 4; ++m)
            #pragma unroll
            for (int n = 0; n < NT; ++n)
                acc[m][n] = __builtin_amdgcn_mfma_f32_16x16x32_bf16(ag[m], bg[n], acc[m][n], 0, 0, 0);
        __syncthreads();
    }

    OutT* Cb = C + (long)bz * bsC + (long)mt * 128 * ldc + nt * BN;
    const float* Rb = RES ? (res + (long)bz * bsC + (long)mt * 128 * ldc + nt * BN) : nullptr;
    #pragma unroll
    for (int n = 0; n < NT; ++n) {
        int col = wn * (BN / 2) + n * 16 + fr;
        float bv = BIAS ? bias[nt * BN + col] : 0.f;
        #pragma unroll
        for (int m = 0; m < 4; ++m) {
            #pragma unroll
            for (int r = 0; r < 4; ++r) {
                int row = wm * 64 + m * 16 + fq * 4 + r;
                float v = acc[m][n][r] * scale + bv;
                if (RES) v += Rb[(long)row * ldc + col];
                if (RELU) v = fmaxf(v, 0.f);
                if constexpr (sizeof(OutT) == 4) Cb[(long)row * ldc + col] = v;
                else                             Cb[(long)row * ldc + col] = f2bf(v);
            }
        }
    }
}

// ---------------- causal softmax over rows of [B,T,T], writes bf16 probs ----------------
__global__ void k_softmax(const float* __restrict__ S, uint16_t* __restrict__ P)
{
    int t = blockIdx.x, b = blockIdx.y;
    const float* row = S + ((long)b * 1024 + t) * 1024;
    uint16_t* pr = P + ((long)b * 1024 + t) * 1024;
    int limit = (t & ~127) + 128;
    int s0 = threadIdx.x * 4;
    float vals[4] = {0.f, 0.f, 0.f, 0.f};
    if (s0 < limit) {
        float4 vv = *(const float4*)(row + s0);
        vals[0] = vv.x; vals[1] = vv.y; vals[2] = vv.z; vals[3] = vv.w;
    }
    float mx = -1e30f;
    #pragma unroll
    for (int j = 0; j < 4; ++j) if (s0 + j <= t) mx = fmaxf(mx, vals[j]);
    #pragma unroll
    for (int o = 32; o; o >>= 1) mx = fmaxf(mx, __shfl_xor(mx, o));
    __shared__ float red[8];
    int wave = threadIdx.x >> 6, lane = threadIdx.x & 63;
    if (lane == 0) red[wave] = mx;
    __syncthreads();
    mx = fmaxf(fmaxf(red[0], red[1]), fmaxf(red[2], red[3]));
    float e[4]; float sum = 0.f;
    #pragma unroll
    for (int j = 0; j < 4; ++j) { e[j] = (s0 + j <= t) ? __expf(vals[j] - mx) : 0.f; sum += e[j]; }
    #pragma unroll
    for (int o = 32; o; o >>= 1) sum += __shfl_xor(sum, o);
    if (lane == 0) red[4 + wave] = sum;
    __syncthreads();
    sum = red[4] + red[5] + red[6] + red[7];
    float inv = 1.f / sum;
    if (s0 < limit) {
        #pragma unroll
        for (int j = 0; j < 4; ++j) pr[s0 + j] = f2bf(e[j] * inv);
    }
}

// ---------------- layernorm of a single f32 tensor: out = LN(a)*w + bias ----------------
__global__ void k_ln(const float* __restrict__ a,
                     const float* __restrict__ w, const float* __restrict__ bias,
                     float* __restrict__ outf, uint16_t* __restrict__ outb)
{
    int row = blockIdx.x;
    const float* ar = a + (long)row * 768;
    float v[3]; float s1 = 0.f, s2 = 0.f;
    #pragma unroll
    for (int i = 0; i < 3; ++i) {
        int e = threadIdx.x + i * 256;
        v[i] = ar[e];
        s1 += v[i]; s2 += v[i] * v[i];
    }
    #pragma unroll
    for (int o = 32; o; o >>= 1) { s1 += __shfl_xor(s1, o); s2 += __shfl_xor(s2, o); }
    __shared__ float red[8];
    int wave = threadIdx.x >> 6, lane = threadIdx.x & 63;
    if (lane == 0) { red[wave] = s1; red[4 + wave] = s2; }
    __syncthreads();
    s1 = red[0] + red[1] + red[2] + red[3];
    s2 = red[4] + red[5] + red[6] + red[7];
    float mean = s1 * (1.f / 768.f);
    float var  = s2 * (1.f / 768.f) - mean * mean;
    float rstd = rsqrtf(var + 1e-5f);
    #pragma unroll
    for (int i = 0; i < 3; ++i) {
        int e = threadIdx.x + i * 256;
        float o = (v[i] - mean) * rstd * w[e] + bias[e];
        outf[(long)row * 768 + e] = o;
        outb[(long)row * 768 + e] = f2bf(o);
    }
}

// ------- layernorm for FFN2 split-K: out = LN(p0+p1+p2+p3 + b2 + h1)*w + bias -------
__global__ void k_ln_ffn2(const float* __restrict__ p, long pstride,
                          const float* __restrict__ b2, const float* __restrict__ h1,
                          const float* __restrict__ w, const float* __restrict__ bias,
                          float* __restrict__ outf, uint16_t* __restrict__ outb)
{
    int row = blockIdx.x;
    long base = (long)row * 768;
    float v[3]; float s1 = 0.f, s2 = 0.f;
    #pragma unroll
    for (int i = 0; i < 3; ++i) {
        int e = threadIdx.x + i * 256;
        float acc = b2[e] + h1[base + e];
        #pragma unroll
        for (int s = 0; s < 4; ++s) acc += p[base + e + s * pstride];
        v[i] = acc;
        s1 += acc; s2 += acc * acc;
    }
    #pragma unroll
    for (int o = 32; o; o >>= 1) { s1 += __shfl_xor(s1, o); s2 += __shfl_xor(s2, o); }
    __shared__ float red[8];
    int wave = threadIdx.x >> 6, lane = threadIdx.x & 63;
    if (lane == 0) { red[wave] = s1; red[4 + wave] = s2; }
    __syncthreads();
    s1 = red[0] + red[1] + red[2] + red[3];
    s2 = red[4] + red[5] + red[6] + red[7];
    float mean = s1 * (1.f / 768.f);
    float var  = s2 * (1.f / 768.f) - mean * mean;
    float rstd = rsqrtf(var + 1e-5f);
    #pragma unroll
    for (int i = 0; i < 3; ++i) {
        int e = threadIdx.x + i * 256;
        float o = (v[i] - mean) * rstd * w[e] + bias[e];
        outf[base + e] = o;
        outb[base + e] = f2bf(o);
    }
}

// ---------------- host ----------------
extern "C" void kernel_launch(void* const* d_in, const int* in_sizes, int n_in,
                              void* d_out, int out_size, void* d_ws, size_t ws_size,
                              hipStream_t stream)
{
    const int*   x       = (const int*)d_in[0];
    const float* tok_emb = (const float*)d_in[1];
    const float* pos_emb = (const float*)d_in[2];
    const float* Wq  = (const float*)d_in[3];
    const float* bq  = (const float*)d_in[4];
    const float* Wk  = (const float*)d_in[5];
    const float* bk  = (const float*)d_in[6];
    const float* Wv  = (const float*)d_in[7];
    const float* bv  = (const float*)d_in[8];
    const float* ln1w = (const float*)d_in[9];
    const float* ln1b = (const float*)d_in[10];
    const float* W1  = (const float*)d_in[11];
    const float* b1  = (const float*)d_in[12];
    const float* W2  = (const float*)d_in[13];
    const float* b2  = (const float*)d_in[14];
    const float* ln2w = (const float*)d_in[15];
    const float* ln2b = (const float*)d_in[16];
    const float* Wo  = (const float*)d_in[17];
    const float* bo  = (const float*)d_in[18];
    float* out = (float*)d_out;
    (void)in_sizes; (void)n_in; (void)out_size;

    char* ws = (char*)d_ws;
    size_t off = 0;
    auto alloc = [&](size_t bytes) -> char* {
        char* p = ws + off;
        off = (off + bytes + 255) & ~(size_t)255;
        return p;
    };
    uint16_t* WoT   = (uint16_t*)alloc(32000L * 768 * 2);
    float*    hf    = (float*)alloc(2048L * 768 * 4);
    uint16_t* hb    = (uint16_t*)alloc(2048L * 768 * 2);
    uint16_t* qkv   = (uint16_t*)alloc(2048L * 2304 * 2);
    uint16_t* vT    = (uint16_t*)alloc(2L * 768 * 1024 * 2);
    float*    sc    = (float*)alloc(2L * 1024 * 1024 * 4);
    uint16_t* pr    = (uint16_t*)alloc(2L * 1024 * 1024 * 2);
    float*    hsum  = (float*)alloc(2048L * 768 * 4);   // h + att (PV residual fused)
    float*    h1f   = (float*)alloc(2048L * 768 * 4);
    uint16_t* h1b   = (uint16_t*)alloc(2048L * 768 * 2);
    uint16_t* f1    = (uint16_t*)alloc(2048L * 3072 * 2);
    float*    f2p   = (float*)alloc(4L * 2048 * 768 * 4); // FFN2 split-K partials
    float*    bqkvA = (float*)alloc(6L * 2304 * 4);
    const long PSTR = 2048L * 768;                        // partial stride (elements)

    // try to hoist all weight transposes (z=6 batched)
    size_t mark = off;
    uint16_t* WqkvTA = (uint16_t*)alloc(6L * 2304 * 768 * 2);
    uint16_t* W1TA   = (uint16_t*)alloc(6L * 3072 * 768 * 2);
    uint16_t* W2TA   = (uint16_t*)alloc(6L * 768 * 3072 * 2);
    bool hoist = (off <= ws_size);
    uint16_t *WqkvT = nullptr, *W1T = nullptr, *W2T = nullptr;
    if (!hoist) {
        off = mark;
        WqkvT = (uint16_t*)alloc(2304L * 768 * 2);
        W1T   = (uint16_t*)alloc(3072L * 768 * 2);
        W2T   = (uint16_t*)alloc(768L * 3072 * 2);
    }

    dim3 tb(32, 8);
    const float iscale = 0.036084391824351615f;  // 1/sqrt(768)
    const long EE = 768L * 768;

    k_transpose<float><<<dim3(1000, 24, 1), tb, 0, stream>>>(Wo, WoT, 32000, 768, 0, 0);
    k_embed<<<2048, 256, 0, stream>>>(x, tok_emb, pos_emb, hf, hb);
    k_concat3<<<dim3(3, 6), 256, 0, stream>>>(bq, bk, bv, bqkvA);

    if (hoist) {
        k_transpose<float><<<dim3(24, 24, 6), tb, 0, stream>>>(Wq, WqkvTA,             768, 768, EE, 2304L*768);
        k_transpose<float><<<dim3(24, 24, 6), tb, 0, stream>>>(Wk, WqkvTA + 768L*768,  768, 768, EE, 2304L*768);
        k_transpose<float><<<dim3(24, 24, 6), tb, 0, stream>>>(Wv, WqkvTA + 1536L*768, 768, 768, EE, 2304L*768);
        k_transpose<float><<<dim3(96, 24, 6), tb, 0, stream>>>(W1, W1TA, 3072, 768, 768L*3072, 3072L*768);
        k_transpose<float><<<dim3(24, 96, 6), tb, 0, stream>>>(W2, W2TA, 768, 3072, 3072L*768, 768L*3072);
    }

    for (int l = 0; l < 6; ++l) {
        uint16_t* WqkvL = hoist ? (WqkvTA + l * 2304L * 768) : WqkvT;
        uint16_t* W1L   = hoist ? (W1TA   + l * 3072L * 768) : W1T;
        uint16_t* W2L   = hoist ? (W2TA   + l * 768L * 3072) : W2T;
        if (!hoist) {
            k_transpose<float><<<dim3(24, 24, 1), tb, 0, stream>>>(Wq + l * EE, WqkvT,             768, 768, 0, 0);
            k_transpose<float><<<dim3(24, 24, 1), tb, 0, stream>>>(Wk + l * EE, WqkvT + 768L*768,  768, 768, 0, 0);
            k_transpose<float><<<dim3(24, 24, 1), tb, 0, stream>>>(Wv + l * EE, WqkvT + 1536L*768, 768, 768, 0, 0);
            k_transpose<float><<<dim3(96, 24, 1), tb, 0, stream>>>(W1 + l * 768L * 3072, W1T, 3072, 768, 0, 0);
            k_transpose<float><<<dim3(24, 96, 1), tb, 0, stream>>>(W2 + l * 3072L * 768, W2T, 768, 3072, 0, 0);
        }

        // qkv = h @ [Wq|Wk|Wv] + bias   [2048, 2304] bf16   (BN=64: 576 blocks)
        k_gemm<uint16_t, 64, true, false, false><<<dim3(36, 16, 1), 256, 0, stream>>>(
            hb, WqkvL, qkv, bqkvA + l * 2304, nullptr, 768, 768, 768, 2304, 0, 0, 0, 1.f, 0);
        // scores = Q @ K^T / sqrt(E), causal tile-skip, f32   (BN=64: 144 active)
        k_gemm<float, 64, false, false, false><<<dim3(16, 8, 2), 256, 0, stream>>>(
            qkv, qkv + 768, sc, nullptr, nullptr, 768, 2304, 2304, 1024,
            1024L * 2304, 1024L * 2304, 1024L * 1024, iscale, 1);
        k_softmax<<<dim3(1024, 2), 256, 0, stream>>>(sc, pr);
        // V^T per batch: src [1024][768] (ld 2304) -> [768][1024]
        k_transpose<uint16_t><<<dim3(24, 32, 2), tb, 0, stream>>>(
            qkv + 1536, vT, 2304, 1024, 1024L * 2304, 768L * 1024);
        // hsum = P @ V + h   (K clamped causally)   (BN=64: 192 blocks)
        k_gemm<float, 64, false, false, true><<<dim3(12, 8, 2), 256, 0, stream>>>(
            pr, vT, hsum, nullptr, hf, 1024, 1024, 1024, 768,
            1024L * 1024, 768L * 1024, 1024L * 768, 1.f, 2);
        k_ln<<<2048, 256, 0, stream>>>(hsum, ln1w + l * 768, ln1b + l * 768, h1f, h1b);
        // f1 = relu(h1 @ W1 + b1)  bf16   (BN=64: 768 blocks)
        k_gemm<uint16_t, 64, true, true, false><<<dim3(48, 16, 1), 256, 0, stream>>>(
            h1b, W1L, f1, b1 + l * 3072, nullptr, 768, 768, 768, 3072, 0, 0, 0, 1.f, 0);
        // FFN2 split-K=4: partials p[z] = f1[:, z*768:(z+1)*768] @ W2T[:, same]  (384 blocks)
        k_gemm<float, 128, false, false, false><<<dim3(6, 16, 4), 256, 0, stream>>>(
            f1, W2L, f2p, nullptr, nullptr, 768, 3072, 3072, 768,
            768, 768, PSTR, 1.f, 0);
        k_ln_ffn2<<<2048, 256, 0, stream>>>(f2p, PSTR, b2 + l * 768, h1f,
                                            ln2w + l * 768, ln2b + l * 768, hf, hb);
    }

    // logits = h @ Wo + bo  -> f32 d_out [2048, 32000]
    k_gemm<float, 128, true, false, false><<<dim3(250, 16, 1), 256, 0, stream>>>(
        hb, WoT, out, bo, nullptr, 768, 768, 768, 32000, 0, 0, 0, 1.f, 0);
}